// Round 9
// baseline (306.219 us; speedup 1.0000x reference)
//
#include <hip/hip_runtime.h>
#include <cstdint>

typedef short v8s __attribute__((ext_vector_type(8)));
typedef float v4f __attribute__((ext_vector_type(4)));
typedef unsigned short u16;

#define M_ROWS 11520
#define K1 512
#define N1 2048       // GEMM1 N padded from 1960
#define C_REAL 1960
#define K2 1984       // GEMM2 K padded from 1960
#define N2 512
#define TPAD 56       // fold-layout t padded 49 -> 56 (16B-aligned rows)
#define PLANE_ELEMS (720 * TPAD)   // 40320 elems = 80,640 B
#define HROW 2016     // one hh row of a plane: 36*56 elems
#define SLP 115       // Sl padded row stride (odd -> conflict-free ki sweeps)

__device__ __forceinline__ u16 f2b(float f) {
  union { float f; unsigned u; } v; v.f = f;
  unsigned r = v.u + 0x7FFFu + ((v.u >> 16) & 1u);   // RNE; inputs finite
  return (u16)(r >> 16);
}
__device__ __forceinline__ float b2f(u16 b) {
  union { unsigned u; float f; } v; v.u = ((unsigned)b) << 16; return v.f;
}

// exact-GELU via Abramowitz-Stegun 7.1.26 erf (|eps|<=1.5e-7): rcp + 5-FMA + exp
__device__ __forceinline__ float gelu_f(float y) {
  float z = fabsf(y) * 0.70710678118654752f;
  float t = __builtin_amdgcn_rcpf(fmaf(0.3275911f, z, 1.0f));
  float p = t * fmaf(t, fmaf(t, fmaf(t, fmaf(t, 1.061405429f, -1.453152027f),
                                     1.421413741f), -0.284496736f), 0.254829592f);
  float e = __builtin_amdgcn_exp2f(-z * z * 1.4426950408889634f);
  float erfz = fmaf(-p, e, 1.0f);
  float cdf = 0.5f * (1.0f + (y < 0.0f ? -erfz : erfz));
  return y * cdf;
}

// async global->LDS, 16B per lane, deposited at wave-uniform base + lane*16
__device__ __forceinline__ void gl2lds16(const u16* g, u16* l) {
  __builtin_amdgcn_global_load_lds(
      (const __attribute__((address_space(1))) unsigned int*)g,
      (__attribute__((address_space(3))) unsigned int*)l, 16, 0, 0);
}

__global__ void cast_x8(const float* __restrict__ x, u16* __restrict__ xb) {
  int i = blockIdx.x * 256 + threadIdx.x;          // 737280 threads, 8 elems each
  const float4 a = ((const float4*)x)[2 * i];
  const float4 b = ((const float4*)x)[2 * i + 1];
  u16 o[8] = {f2b(a.x), f2b(a.y), f2b(a.z), f2b(a.w),
              f2b(b.x), f2b(b.y), f2b(b.z), f2b(b.w)};
  ((int4*)xb)[i] = *(const int4*)o;
}

// dst[n][k] = (k < R && n < C) ? src[k*C + n] : 0   (bf16 out, LDS 32x33 tiles)
__global__ __launch_bounds__(256) void transpose_cast(
    const float* __restrict__ src, u16* __restrict__ dst, int R, int C, int KP)
{
  __shared__ float T[32][33];
  const int n0 = blockIdx.x * 32, k0 = blockIdx.y * 32;
  const int tx = threadIdx.x & 31, ty = threadIdx.x >> 5;
  #pragma unroll
  for (int r = 0; r < 4; ++r) {
    int k = k0 + ty + 8 * r, n = n0 + tx;
    T[ty + 8 * r][tx] = (k < R && n < C) ? src[(size_t)k * C + n] : 0.f;
  }
  __syncthreads();
  #pragma unroll
  for (int r = 0; r < 4; ++r) {
    int n = n0 + ty + 8 * r, k = k0 + tx;
    if (k < KP) dst[(size_t)n * KP + k] = f2b(T[tx][ty + 8 * r]);
  }
}

__global__ void zero_gpad(u16* __restrict__ G) {
  int i = blockIdx.x * 256 + threadIdx.x;   // 11520*24
  int r = i / 24, j = i - r * 24;
  G[(size_t)r * K2 + C_REAL + j] = 0;
}

__device__ __forceinline__ void stv(float v, float* p) { *p = v; }
__device__ __forceinline__ void stv(float v, u16* p) { *p = f2b(v); }

// ------- bf16 MFMA GEMM: C = A(MxK) @ BT(NxK)^T + bias
// 128x128 tile, BK=64, global_load_lds width-16 staging, XOR bank swizzle.
// FOLD=true: emit bf16 into plane-major fold layout Aw[bt*40+ch][v][t] (t pad 56).
template<typename OT, bool FOLD>
__global__ __launch_bounds__(256) void gemm_bt(
    const u16* __restrict__ A, const u16* __restrict__ BT,
    const float* __restrict__ bias, int nb, OT* __restrict__ C, int N, int K)
{
  __shared__ u16 As[128 * 64];
  __shared__ u16 Bs[128 * 64];
  const int tid = threadIdx.x;
  const int bm = blockIdx.y * 128, bn = blockIdx.x * 128;
  const int wave = tid >> 6, lane = tid & 63;
  const int quad = lane >> 4, l16 = lane & 15;
  const int wm = (wave >> 1) * 64, wn = (wave & 1) * 64;
  const int srow = lane >> 3;                      // 0..7
  const int scol = ((lane & 7) ^ srow) * 8;        // swizzled source chunk

  const u16* pA = A + (size_t)(bm + wave * 32 + srow) * K + scol;
  const u16* pB = BT + (size_t)(bn + wave * 32 + srow) * K + scol;
  u16* lA = As + (wave * 32) * 64;
  u16* lB = Bs + (wave * 32) * 64;

  v4f acc[4][4];
  #pragma unroll
  for (int i = 0; i < 4; ++i)
    #pragma unroll
    for (int j = 0; j < 4; ++j) acc[i][j] = (v4f){0.f, 0.f, 0.f, 0.f};

  for (int k0 = 0; k0 < K; k0 += 64) {
    #pragma unroll
    for (int q = 0; q < 4; ++q) {
      gl2lds16(pA + (size_t)(q * 8) * K, lA + q * 8 * 64);
      gl2lds16(pB + (size_t)(q * 8) * K, lB + q * 8 * 64);
    }
    pA += 64; pB += 64;
    __syncthreads();
    #pragma unroll
    for (int h = 0; h < 2; ++h) {
      v8s af[4], bf[4];
      #pragma unroll
      for (int i = 0; i < 4; ++i) {
        int row = wm + i * 16 + l16;
        int ck = (h * 4 + quad) ^ (row & 7);
        af[i] = *(const v8s*)&As[row * 64 + ck * 8];
      }
      #pragma unroll
      for (int j = 0; j < 4; ++j) {
        int row = wn + j * 16 + l16;
        int ck = (h * 4 + quad) ^ (row & 7);
        bf[j] = *(const v8s*)&Bs[row * 64 + ck * 8];
      }
      #pragma unroll
      for (int i = 0; i < 4; ++i)
        #pragma unroll
        for (int j = 0; j < 4; ++j)
          acc[i][j] = __builtin_amdgcn_mfma_f32_16x16x32_bf16(af[i], bf[j], acc[i][j], 0, 0, 0);
    }
    __syncthreads();
  }

  #pragma unroll
  for (int i = 0; i < 4; ++i) {
    #pragma unroll
    for (int j = 0; j < 4; ++j) {
      int col = bn + wn + j * 16 + l16;
      if (FOLD && col >= C_REAL) continue;
      float bv = (col < nb) ? bias[col] : 0.f;
      int ch = 0, t = 0;
      if (FOLD) { ch = col / 49; t = col - ch * 49; }
      #pragma unroll
      for (int r = 0; r < 4; ++r) {
        int row = bm + wm + i * 16 + quad * 4 + r;
        float val = acc[i][j][r] + bv;
        if (FOLD) {
          int bt = row / 720, v = row - bt * 720;
          stv(val, C + (size_t)(bt * 40 + ch) * PLANE_ELEMS + v * TPAD + t);
        } else {
          stv(val, C + (size_t)row * N + col);
        }
      }
    }
  }
}

// ------- GEMM2 variant: 128x64 tile (better occupancy for N=512 -> 720 blocks)
// Wave w: 64x32 quadrant (wm=(w>>1)*64, wn=(w&1)*32), acc 4x2.
__global__ __launch_bounds__(256) void gemm_bt64(
    const u16* __restrict__ A, const u16* __restrict__ BT,
    const float* __restrict__ bias, float* __restrict__ C, int N, int K)
{
  __shared__ u16 As[128 * 64];
  __shared__ u16 Bs[64 * 64];
  const int tid = threadIdx.x;
  const int bm = blockIdx.y * 128, bn = blockIdx.x * 64;
  const int wave = tid >> 6, lane = tid & 63;
  const int quad = lane >> 4, l16 = lane & 15;
  const int wm = (wave >> 1) * 64, wn = (wave & 1) * 32;
  const int srow = lane >> 3;
  const int scol = ((lane & 7) ^ srow) * 8;

  const u16* pA = A + (size_t)(bm + wave * 32 + srow) * K + scol;
  const u16* pB = BT + (size_t)(bn + wave * 16 + srow) * K + scol;
  u16* lA = As + (wave * 32) * 64;
  u16* lB = Bs + (wave * 16) * 64;

  v4f acc[4][2];
  #pragma unroll
  for (int i = 0; i < 4; ++i)
    #pragma unroll
    for (int j = 0; j < 2; ++j) acc[i][j] = (v4f){0.f, 0.f, 0.f, 0.f};

  for (int k0 = 0; k0 < K; k0 += 64) {
    #pragma unroll
    for (int q = 0; q < 4; ++q)
      gl2lds16(pA + (size_t)(q * 8) * K, lA + q * 8 * 64);
    #pragma unroll
    for (int q = 0; q < 2; ++q)
      gl2lds16(pB + (size_t)(q * 8) * K, lB + q * 8 * 64);
    pA += 64; pB += 64;
    __syncthreads();
    #pragma unroll
    for (int h = 0; h < 2; ++h) {
      v8s af[4], bf[2];
      #pragma unroll
      for (int i = 0; i < 4; ++i) {
        int row = wm + i * 16 + l16;
        int ck = (h * 4 + quad) ^ (row & 7);
        af[i] = *(const v8s*)&As[row * 64 + ck * 8];
      }
      #pragma unroll
      for (int j = 0; j < 2; ++j) {
        int row = wn + j * 16 + l16;
        int ck = (h * 4 + quad) ^ (row & 7);
        bf[j] = *(const v8s*)&Bs[row * 64 + ck * 8];
      }
      #pragma unroll
      for (int i = 0; i < 4; ++i)
        #pragma unroll
        for (int j = 0; j < 2; ++j)
          acc[i][j] = __builtin_amdgcn_mfma_f32_16x16x32_bf16(af[i], bf[j], acc[i][j], 0, 0, 0);
    }
    __syncthreads();
  }

  #pragma unroll
  for (int i = 0; i < 4; ++i) {
    #pragma unroll
    for (int j = 0; j < 2; ++j) {
      int col = bn + wn + j * 16 + l16;
      float bv = bias[col];
      #pragma unroll
      for (int r = 0; r < 4; ++r) {
        int row = bm + wm + i * 16 + quad * 4 + r;
        C[(size_t)row * N + col] = acc[i][j][r] + bv;
      }
    }
  }
}

// ------- fold + normalize, gather formulation, strip granularity (grid 3x640)
__global__ __launch_bounds__(256) void fold_norm(const u16* __restrict__ Aw,
                                                 float* __restrict__ Sn)
{
  __shared__ u16 raw[10 * HROW];          // 40,320 B
  const int plane = blockIdx.y;
  const int r0 = blockIdx.x * 22;
  const int tid = threadIdx.x;
  const int hlo = max(0, (r0 - 6) / 3);
  const int hhi = min(19, (r0 + 21) / 3);
  const int nchunks = (hhi - hlo + 1) * (HROW / 8);
  const int4* src = (const int4*)(Aw + (size_t)plane * PLANE_ELEMS + hlo * HROW);
  int4* dst = (int4*)raw;
  for (int j = tid; j < nchunks; j += 256) dst[j] = src[j];
  __syncthreads();

  float* out = Sn + (size_t)plane * 7524 + r0 * 114;
  for (int i = tid; i < 22 * 114; i += 256) {
    int r = i / 114, px = i - r * 114;
    int py = r0 + r;
    float val = 0.f;
    if (py >= 3 && py < 63 && px >= 3 && px < 111) {
      int ry = py % 3, rx = px % 3;
      int hhs[3], kis[3], nki = 0;
      #pragma unroll
      for (int k = 0; k < 3; ++k) {
        int ki = ry + 3 * k;
        if (ki < 7 && py - ki >= 0) {
          int hh = (py - ki) / 3;
          if (hh < 20) { kis[nki] = ki; hhs[nki] = hh; ++nki; }
        }
      }
      int wws[3], kjs[3], nkj = 0;
      #pragma unroll
      for (int k = 0; k < 3; ++k) {
        int kj = rx + 3 * k;
        if (kj < 7 && px - kj >= 0) {
          int ww = (px - kj) / 3;
          if (ww < 36) { kjs[nkj] = kj; wws[nkj] = ww; ++nkj; }
        }
      }
      float sum = 0.f;
      for (int a = 0; a < nki; ++a) {
        int rowoff = (hhs[a] - hlo) * HROW + kis[a] * 7;
        for (int b = 0; b < nkj; ++b)
          sum += b2f(raw[rowoff + wws[b] * TPAD + kjs[b]]);
      }
      val = sum / (float)(nki * nkj);
    }
    out[i] = val;
  }
}

// ------- rolling-window dwconv + GELU from Snorm strips; grid (5, 640)
template<int KS>
__device__ __forceinline__ void conv_part(const float* __restrict__ Sl,
    const float* __restrict__ Wl, const float* __restrict__ Bl,
    u16* __restrict__ G, int bt, int colbase, int h0, int tid)
{
  constexpr int P = KS / 2;
  const int rbase = 3 * h0 - 6;          // Sl row 0 == Snorm row rbase
  for (int idx = tid; idx < 36 * 49; idx += 256) {
    int wo = idx / 49, t = idx - wo * 49;
    int ki = t / 7, kj = t - ki * 7;
    float wgt[KS * KS];
    #pragma unroll
    for (int j = 0; j < KS * KS; ++j) wgt[j] = Wl[t * KS * KS + j];
    const float bias = Bl[t];
    int sx[KS]; bool vx[KS];
    #pragma unroll
    for (int dx = 0; dx < KS; ++dx) {
      int wq = wo + dx - P;
      vx[dx] = (wq >= 0 && wq < 36);
      sx[dx] = wq * 3 + kj;
    }
    float win[KS][KS];
    #pragma unroll
    for (int dy = 0; dy < KS; ++dy) {
      int hq = h0 + dy - P;
      #pragma unroll
      for (int dx = 0; dx < KS; ++dx)
        win[dy][dx] = (hq >= 0 && hq < 20 && vx[dx])
                        ? Sl[(hq * 3 + ki - rbase) * SLP + sx[dx]] : 0.f;
    }
    u16* gp = G + (size_t)(bt * 720 + h0 * 36 + wo) * K2 + colbase + t;
    #pragma unroll
    for (int hh = 0; hh < 4; ++hh) {
      float y = bias;
      #pragma unroll
      for (int dy = 0; dy < KS; ++dy)
        #pragma unroll
        for (int dx = 0; dx < KS; ++dx)
          y += wgt[dy * KS + dx] * win[dy][dx];
      *gp = f2b(gelu_f(y));
      gp += (size_t)36 * K2;
      if (hh < 3) {
        #pragma unroll
        for (int dy = 0; dy < KS - 1; ++dy)
          #pragma unroll
          for (int dx = 0; dx < KS; ++dx) win[dy][dx] = win[dy + 1][dx];
        int hq = h0 + hh + 1 + P;
        #pragma unroll
        for (int dx = 0; dx < KS; ++dx)
          win[KS - 1][dx] = (hq < 20 && vx[dx])
                              ? Sl[(hq * 3 + ki - rbase) * SLP + sx[dx]] : 0.f;
      }
    }
  }
}

__global__ __launch_bounds__(256) void dwconv_gelu2(const float* __restrict__ Sn,
    const float* __restrict__ w3, const float* __restrict__ b3,
    const float* __restrict__ w5, const float* __restrict__ b5,
    u16* __restrict__ G)
{
  __shared__ float Sl[28 * SLP];     // Snorm rows [3h0-6, 3h0+21], stride 115
  __shared__ float Wl[49 * 25];
  __shared__ float Bl[49];
  const int plane = blockIdx.y, bt = plane / 40, ch = plane % 40;
  const int h0 = blockIdx.x * 4;
  const int tid = threadIdx.x;
  const int colbase = ch * 49;
  const bool is3 = (ch < 20);
  if (is3) {
    for (int i = tid; i < 49 * 9; i += 256) Wl[i] = w3[colbase * 9 + i];
    if (tid < 49) Bl[tid] = b3[colbase + tid];
  } else {
    int c5 = colbase - 980;
    for (int i = tid; i < 49 * 25; i += 256) Wl[i] = w5[c5 * 25 + i];
    if (tid < 49) Bl[tid] = b5[c5 + tid];
  }
  const int rbase = 3 * h0 - 6;
  const float* sp = Sn + (size_t)plane * 7524;
  for (int i = tid; i < 28 * 114; i += 256) {
    int r = i / 114, c = i - r * 114;
    int py = rbase + r;
    Sl[r * SLP + c] = (py >= 0 && py < 66) ? sp[py * 114 + c] : 0.f;
  }
  __syncthreads();
  if (is3) conv_part<3>(Sl, Wl, Bl, G, bt, colbase, h0, tid);
  else     conv_part<5>(Sl, Wl, Bl, G, bt, colbase, h0, tid);
}

extern "C" void kernel_launch(void* const* d_in, const int* in_sizes, int n_in,
                              void* d_out, int out_size, void* d_ws, size_t ws_size,
                              hipStream_t stream) {
  const float* x  = (const float*)d_in[0];
  const float* w1 = (const float*)d_in[1];
  const float* b1 = (const float*)d_in[2];
  const float* w3 = (const float*)d_in[3];
  const float* b3 = (const float*)d_in[4];
  const float* w5 = (const float*)d_in[5];
  const float* b5 = (const float*)d_in[6];
  const float* w2 = (const float*)d_in[7];
  const float* b2 = (const float*)d_in[8];
  float* out = (float*)d_out;

  char* ws = (char*)d_ws;
  u16*   Xb  = (u16*)(ws);                   // 11520*512  bf16 = 11,796,480
  u16*   W1T = (u16*)(ws + 11796480);        // 2048*512   bf16 =  2,097,152
  u16*   W2T = (u16*)(ws + 13893632);        // 512*1984   bf16 =  2,031,616
  u16*   Aw  = (u16*)(ws + 15925248);        // 640*40320  bf16 = 51,609,600 (fold layout)
  u16*   G   = (u16*)(ws + 67534848);        // 11520*1984 bf16 = 45,711,360
  float* Sn  = (float*)(ws + 113246208);     // 640*7524   fp32 = 19,261,440 -> 132,507,648 total

  hipLaunchKernelGGL(cast_x8, dim3(2880), dim3(256), 0, stream, x, Xb);
  hipLaunchKernelGGL(transpose_cast, dim3(64, 16), dim3(256), 0, stream, w1, W1T, K1, C_REAL, K1);
  hipLaunchKernelGGL(transpose_cast, dim3(16, 62), dim3(256), 0, stream, w2, W2T, C_REAL, N2, K2);
  hipLaunchKernelGGL(zero_gpad, dim3(1080), dim3(256), 0, stream, G);
  hipLaunchKernelGGL((gemm_bt<u16, true>), dim3(N1 / 128, M_ROWS / 128), dim3(256), 0, stream,
                     Xb, W1T, b1, C_REAL, Aw, N1, K1);
  hipLaunchKernelGGL(fold_norm, dim3(3, 640), dim3(256), 0, stream, Aw, Sn);
  hipLaunchKernelGGL(dwconv_gelu2, dim3(5, 640), dim3(256), 0, stream,
                     Sn, w3, b3, w5, b5, G);
  hipLaunchKernelGGL(gemm_bt64, dim3(N2 / 64, M_ROWS / 128), dim3(256), 0, stream,
                     G, W2T, b2, out, N2, K2);
}

// Round 10
// 272.412 us; speedup vs baseline: 1.1241x; 1.1241x over previous
//
#include <hip/hip_runtime.h>
#include <cstdint>

typedef short v8s __attribute__((ext_vector_type(8)));
typedef float v4f __attribute__((ext_vector_type(4)));
typedef unsigned short u16;

#define M_ROWS 11520
#define K1 512
#define N1 2048       // GEMM1 N padded from 1960
#define C_REAL 1960
#define K2 1984       // GEMM2 K padded from 1960
#define N2 512
#define TPAD 56       // fold-layout t padded 49 -> 56 (16B-aligned rows)
#define PLANE_ELEMS (720 * TPAD)   // 40320 elems = 80,640 B
#define HROW 2016     // one hh row of a plane: 36*56 elems

__device__ __forceinline__ u16 f2b(float f) {
  union { float f; unsigned u; } v; v.f = f;
  unsigned r = v.u + 0x7FFFu + ((v.u >> 16) & 1u);   // RNE; inputs finite
  return (u16)(r >> 16);
}
__device__ __forceinline__ float b2f(u16 b) {
  union { unsigned u; float f; } v; v.u = ((unsigned)b) << 16; return v.f;
}

// async global->LDS, 16B per lane, deposited at wave-uniform base + lane*16
__device__ __forceinline__ void gl2lds16(const u16* g, u16* l) {
  __builtin_amdgcn_global_load_lds(
      (const __attribute__((address_space(1))) unsigned int*)g,
      (__attribute__((address_space(3))) unsigned int*)l, 16, 0, 0);
}

__global__ void cast_x8(const float* __restrict__ x, u16* __restrict__ xb) {
  int i = blockIdx.x * 256 + threadIdx.x;          // 737280 threads, 8 elems each
  const float4 a = ((const float4*)x)[2 * i];
  const float4 b = ((const float4*)x)[2 * i + 1];
  u16 o[8] = {f2b(a.x), f2b(a.y), f2b(a.z), f2b(a.w),
              f2b(b.x), f2b(b.y), f2b(b.z), f2b(b.w)};
  ((int4*)xb)[i] = *(const int4*)o;
}

// dst[n][k] = (k < R && n < C) ? src[k*C + n] : 0   (bf16 out, LDS 32x33 tiles)
__global__ __launch_bounds__(256) void transpose_cast(
    const float* __restrict__ src, u16* __restrict__ dst, int R, int C, int KP)
{
  __shared__ float T[32][33];
  const int n0 = blockIdx.x * 32, k0 = blockIdx.y * 32;
  const int tx = threadIdx.x & 31, ty = threadIdx.x >> 5;
  #pragma unroll
  for (int r = 0; r < 4; ++r) {
    int k = k0 + ty + 8 * r, n = n0 + tx;
    T[ty + 8 * r][tx] = (k < R && n < C) ? src[(size_t)k * C + n] : 0.f;
  }
  __syncthreads();
  #pragma unroll
  for (int r = 0; r < 4; ++r) {
    int n = n0 + ty + 8 * r, k = k0 + tx;
    if (k < KP) dst[(size_t)n * KP + k] = f2b(T[tx][ty + 8 * r]);
  }
}

__global__ void zero_gpad(u16* __restrict__ G) {
  int i = blockIdx.x * 256 + threadIdx.x;   // 11520*24
  int r = i / 24, j = i - r * 24;
  G[(size_t)r * K2 + C_REAL + j] = 0;
}

__device__ __forceinline__ void stv(float v, float* p) { *p = v; }
__device__ __forceinline__ void stv(float v, u16* p) { *p = f2b(v); }

// ------- bf16 MFMA GEMM: C = A(MxK) @ BT(NxK)^T + bias
// 128x128 tile, BK=64, global_load_lds width-16 staging, XOR bank swizzle.
// FOLD=true: emit bf16 into plane-major fold layout Aw[bt*40+ch][v][t] (t pad 56).
template<typename OT, bool FOLD>
__global__ __launch_bounds__(256) void gemm_bt(
    const u16* __restrict__ A, const u16* __restrict__ BT,
    const float* __restrict__ bias, int nb, OT* __restrict__ C, int N, int K)
{
  __shared__ u16 As[128 * 64];
  __shared__ u16 Bs[128 * 64];
  const int tid = threadIdx.x;
  const int bm = blockIdx.y * 128, bn = blockIdx.x * 128;
  const int wave = tid >> 6, lane = tid & 63;
  const int quad = lane >> 4, l16 = lane & 15;
  const int wm = (wave >> 1) * 64, wn = (wave & 1) * 64;
  const int srow = lane >> 3;                      // 0..7
  const int scol = ((lane & 7) ^ srow) * 8;        // swizzled source chunk

  const u16* pA = A + (size_t)(bm + wave * 32 + srow) * K + scol;
  const u16* pB = BT + (size_t)(bn + wave * 32 + srow) * K + scol;
  u16* lA = As + (wave * 32) * 64;
  u16* lB = Bs + (wave * 32) * 64;

  v4f acc[4][4];
  #pragma unroll
  for (int i = 0; i < 4; ++i)
    #pragma unroll
    for (int j = 0; j < 4; ++j) acc[i][j] = (v4f){0.f, 0.f, 0.f, 0.f};

  for (int k0 = 0; k0 < K; k0 += 64) {
    #pragma unroll
    for (int q = 0; q < 4; ++q) {
      gl2lds16(pA + (size_t)(q * 8) * K, lA + q * 8 * 64);
      gl2lds16(pB + (size_t)(q * 8) * K, lB + q * 8 * 64);
    }
    pA += 64; pB += 64;
    __syncthreads();
    #pragma unroll
    for (int h = 0; h < 2; ++h) {
      v8s af[4], bf[4];
      #pragma unroll
      for (int i = 0; i < 4; ++i) {
        int row = wm + i * 16 + l16;
        int ck = (h * 4 + quad) ^ (row & 7);
        af[i] = *(const v8s*)&As[row * 64 + ck * 8];
      }
      #pragma unroll
      for (int j = 0; j < 4; ++j) {
        int row = wn + j * 16 + l16;
        int ck = (h * 4 + quad) ^ (row & 7);
        bf[j] = *(const v8s*)&Bs[row * 64 + ck * 8];
      }
      #pragma unroll
      for (int i = 0; i < 4; ++i)
        #pragma unroll
        for (int j = 0; j < 4; ++j)
          acc[i][j] = __builtin_amdgcn_mfma_f32_16x16x32_bf16(af[i], bf[j], acc[i][j], 0, 0, 0);
    }
    __syncthreads();
  }

  #pragma unroll
  for (int i = 0; i < 4; ++i) {
    #pragma unroll
    for (int j = 0; j < 4; ++j) {
      int col = bn + wn + j * 16 + l16;
      if (FOLD && col >= C_REAL) continue;
      float bv = (col < nb) ? bias[col] : 0.f;
      int ch = 0, t = 0;
      if (FOLD) { ch = col / 49; t = col - ch * 49; }
      #pragma unroll
      for (int r = 0; r < 4; ++r) {
        int row = bm + wm + i * 16 + quad * 4 + r;
        float val = acc[i][j][r] + bv;
        if (FOLD) {
          int bt = row / 720, v = row - bt * 720;
          stv(val, C + (size_t)(bt * 40 + ch) * PLANE_ELEMS + v * TPAD + t);
        } else {
          stv(val, C + (size_t)row * N + col);
        }
      }
    }
  }
}

// ------- fold + normalize, gather formulation, strip granularity (grid 3x640)
__global__ __launch_bounds__(256) void fold_norm(const u16* __restrict__ Aw,
                                                 float* __restrict__ Sn)
{
  __shared__ u16 raw[10 * HROW];          // 40,320 B
  const int plane = blockIdx.y;
  const int r0 = blockIdx.x * 22;
  const int tid = threadIdx.x;
  const int hlo = max(0, (r0 - 6) / 3);
  const int hhi = min(19, (r0 + 21) / 3);
  const int nchunks = (hhi - hlo + 1) * (HROW / 8);
  const int4* src = (const int4*)(Aw + (size_t)plane * PLANE_ELEMS + hlo * HROW);
  int4* dst = (int4*)raw;
  for (int j = tid; j < nchunks; j += 256) dst[j] = src[j];
  __syncthreads();

  float* out = Sn + (size_t)plane * 7524 + r0 * 114;
  for (int i = tid; i < 22 * 114; i += 256) {
    int r = i / 114, px = i - r * 114;
    int py = r0 + r;
    float val = 0.f;
    if (py >= 3 && py < 63 && px >= 3 && px < 111) {
      int ry = py % 3, rx = px % 3;
      int hhs[3], kis[3], nki = 0;
      #pragma unroll
      for (int k = 0; k < 3; ++k) {
        int ki = ry + 3 * k;
        if (ki < 7 && py - ki >= 0) {
          int hh = (py - ki) / 3;
          if (hh < 20) { kis[nki] = ki; hhs[nki] = hh; ++nki; }
        }
      }
      int wws[3], kjs[3], nkj = 0;
      #pragma unroll
      for (int k = 0; k < 3; ++k) {
        int kj = rx + 3 * k;
        if (kj < 7 && px - kj >= 0) {
          int ww = (px - kj) / 3;
          if (ww < 36) { kjs[nkj] = kj; wws[nkj] = ww; ++nkj; }
        }
      }
      float sum = 0.f;
      for (int a = 0; a < nki; ++a) {
        int rowoff = (hhs[a] - hlo) * HROW + kis[a] * 7;
        for (int b = 0; b < nkj; ++b)
          sum += b2f(raw[rowoff + wws[b] * TPAD + kjs[b]]);
      }
      val = sum / (float)(nki * nkj);
    }
    out[i] = val;
  }
}

// ------- full-height rolling-window dwconv + GELU: 20 output rows per column.
// One block per plane (512 thr), full 66x114 Snorm plane in LDS. Per-column
// overhead (window setup + weight regs + predicates) amortized over 20 rows.
template<int KS>
__device__ __forceinline__ void conv_col(const float* __restrict__ Sl,
    const float* __restrict__ Wl, const float* __restrict__ Bl,
    u16* __restrict__ G, int bt, int colbase, int tid)
{
  constexpr int P = KS / 2;
  for (int idx = tid; idx < 36 * 49; idx += 512) {
    int wo = idx / 49, t = idx - wo * 49;
    int ki = t / 7, kj = t - ki * 7;
    float wgt[KS * KS];
    #pragma unroll
    for (int j = 0; j < KS * KS; ++j) wgt[j] = Wl[t * KS * KS + j];
    const float bias = Bl[t];
    int sx[KS]; bool vx[KS];
    #pragma unroll
    for (int dx = 0; dx < KS; ++dx) {
      int wq = wo + dx - P;
      vx[dx] = (wq >= 0 && wq < 36);
      sx[dx] = wq * 3 + kj;
    }
    float win[KS][KS];
    #pragma unroll
    for (int dy = 0; dy < KS; ++dy) {
      int hq = dy - P;
      #pragma unroll
      for (int dx = 0; dx < KS; ++dx)
        win[dy][dx] = (hq >= 0 && vx[dx]) ? Sl[(hq * 3 + ki) * 114 + sx[dx]] : 0.f;
    }
    u16* gp = G + (size_t)(bt * 720 + wo) * K2 + colbase + t;
    for (int h = 0; h < 20; ++h) {
      float y = bias;
      #pragma unroll
      for (int dy = 0; dy < KS; ++dy)
        #pragma unroll
        for (int dx = 0; dx < KS; ++dx)
          y += wgt[dy * KS + dx] * win[dy][dx];
      float g = 0.5f * y * (1.0f + erff(y * 0.70710678118654752f));
      *gp = f2b(g);
      gp += (size_t)36 * K2;
      if (h < 19) {
        #pragma unroll
        for (int dy = 0; dy < KS - 1; ++dy)
          #pragma unroll
          for (int dx = 0; dx < KS; ++dx) win[dy][dx] = win[dy + 1][dx];
        int hq = h + 1 + P;
        #pragma unroll
        for (int dx = 0; dx < KS; ++dx)
          win[KS - 1][dx] = (hq < 20 && vx[dx])
                              ? Sl[(hq * 3 + ki) * 114 + sx[dx]] : 0.f;
      }
    }
  }
}

__global__ __launch_bounds__(512) void dwconv_gelu3(const float* __restrict__ Sn,
    const float* __restrict__ w3, const float* __restrict__ b3,
    const float* __restrict__ w5, const float* __restrict__ b5,
    u16* __restrict__ G)
{
  __shared__ float Sl[66 * 114];     // 30,096 B
  __shared__ float Wl[49 * 25];
  __shared__ float Bl[49];
  const int plane = blockIdx.x, bt = plane / 40, ch = plane % 40;
  const int tid = threadIdx.x;
  const int colbase = ch * 49;
  const bool is3 = (ch < 20);
  if (is3) {
    for (int i = tid; i < 49 * 9; i += 512) Wl[i] = w3[colbase * 9 + i];
    if (tid < 49) Bl[tid] = b3[colbase + tid];
  } else {
    int c5 = colbase - 980;
    for (int i = tid; i < 49 * 25; i += 512) Wl[i] = w5[c5 * 25 + i];
    if (tid < 49) Bl[tid] = b5[c5 + tid];
  }
  const float4* sp = (const float4*)(Sn + (size_t)plane * 7524);
  float4* sl4 = (float4*)Sl;
  for (int i = tid; i < 7524 / 4; i += 512) sl4[i] = sp[i];
  __syncthreads();
  if (is3) conv_col<3>(Sl, Wl, Bl, G, bt, colbase, tid);
  else     conv_col<5>(Sl, Wl, Bl, G, bt, colbase, tid);
}

extern "C" void kernel_launch(void* const* d_in, const int* in_sizes, int n_in,
                              void* d_out, int out_size, void* d_ws, size_t ws_size,
                              hipStream_t stream) {
  const float* x  = (const float*)d_in[0];
  const float* w1 = (const float*)d_in[1];
  const float* b1 = (const float*)d_in[2];
  const float* w3 = (const float*)d_in[3];
  const float* b3 = (const float*)d_in[4];
  const float* w5 = (const float*)d_in[5];
  const float* b5 = (const float*)d_in[6];
  const float* w2 = (const float*)d_in[7];
  const float* b2 = (const float*)d_in[8];
  float* out = (float*)d_out;

  char* ws = (char*)d_ws;
  u16*   Xb  = (u16*)(ws);                   // 11520*512  bf16 = 11,796,480
  u16*   W1T = (u16*)(ws + 11796480);        // 2048*512   bf16 =  2,097,152
  u16*   W2T = (u16*)(ws + 13893632);        // 512*1984   bf16 =  2,031,616
  u16*   Aw  = (u16*)(ws + 15925248);        // 640*40320  bf16 = 51,609,600 (fold layout)
  u16*   G   = (u16*)(ws + 67534848);        // 11520*1984 bf16 = 45,711,360
  float* Sn  = (float*)(ws + 113246208);     // 640*7524   fp32 = 19,261,440 -> 132,507,648 total

  hipLaunchKernelGGL(cast_x8, dim3(2880), dim3(256), 0, stream, x, Xb);
  hipLaunchKernelGGL(transpose_cast, dim3(64, 16), dim3(256), 0, stream, w1, W1T, K1, C_REAL, K1);
  hipLaunchKernelGGL(transpose_cast, dim3(16, 62), dim3(256), 0, stream, w2, W2T, C_REAL, N2, K2);
  hipLaunchKernelGGL(zero_gpad, dim3(1080), dim3(256), 0, stream, G);
  hipLaunchKernelGGL((gemm_bt<u16, true>), dim3(N1 / 128, M_ROWS / 128), dim3(256), 0, stream,
                     Xb, W1T, b1, C_REAL, Aw, N1, K1);
  hipLaunchKernelGGL(fold_norm, dim3(3, 640), dim3(256), 0, stream, Aw, Sn);
  hipLaunchKernelGGL(dwconv_gelu3, dim3(640), dim3(512), 0, stream,
                     Sn, w3, b3, w5, b5, G);
  hipLaunchKernelGGL((gemm_bt<float, false>), dim3(N2 / 128, M_ROWS / 128), dim3(256), 0, stream,
                     G, W2T, b2, N2, out, N2, K2);
}

// Round 11
// 259.000 us; speedup vs baseline: 1.1823x; 1.0518x over previous
//
#include <hip/hip_runtime.h>
#include <cstdint>

typedef short v8s __attribute__((ext_vector_type(8)));
typedef float v4f __attribute__((ext_vector_type(4)));
typedef unsigned short u16;

#define M_ROWS 11520
#define K1 512
#define N1 2048       // GEMM1 N padded from 1960
#define C_REAL 1960
#define K2 1984       // GEMM2 K padded from 1960
#define N2 512
#define TPAD 56       // fold-layout t padded 49 -> 56 (16B-aligned rows)
#define PLANE_ELEMS (720 * TPAD)   // 40320 elems = 80,640 B
#define HROW 2016     // one hh row of a plane: 36*56 elems

__device__ __forceinline__ u16 f2b(float f) {
  union { float f; unsigned u; } v; v.f = f;
  unsigned r = v.u + 0x7FFFu + ((v.u >> 16) & 1u);   // RNE; inputs finite
  return (u16)(r >> 16);
}
__device__ __forceinline__ float b2f(u16 b) {
  union { unsigned u; float f; } v; v.u = ((unsigned)b) << 16; return v.f;
}

// async global->LDS, 16B per lane, deposited at wave-uniform base + lane*16
__device__ __forceinline__ void gl2lds16(const u16* g, u16* l) {
  __builtin_amdgcn_global_load_lds(
      (const __attribute__((address_space(1))) unsigned int*)g,
      (__attribute__((address_space(3))) unsigned int*)l, 16, 0, 0);
}

// ------- merged prep: cast x -> bf16 | transpose-cast w1,w2 | zero G K-pad.
// Block ranges: [0,2880) cast | [2880,3904) w1T | [3904,4896) w2T | [4896,5976) zero.
__global__ __launch_bounds__(256) void prep(
    const float* __restrict__ x,  u16* __restrict__ xb,
    const float* __restrict__ w1, u16* __restrict__ W1T,
    const float* __restrict__ w2, u16* __restrict__ W2T,
    u16* __restrict__ G)
{
  __shared__ float T[32][33];
  int b = blockIdx.x;
  const int tid = threadIdx.x;
  if (b < 2880) {                      // cast x (8 elems/thread)
    int i = b * 256 + tid;
    const float4 a = ((const float4*)x)[2 * i];
    const float4 c = ((const float4*)x)[2 * i + 1];
    u16 o[8] = {f2b(a.x), f2b(a.y), f2b(a.z), f2b(a.w),
                f2b(c.x), f2b(c.y), f2b(c.z), f2b(c.w)};
    ((int4*)xb)[i] = *(const int4*)o;
    return;
  }
  b -= 2880;
  const float* src; u16* dst; int R, C, KP, n0, k0;
  if (b < 1024) {                      // w1 (512x1960) -> W1T (2048x512)
    src = w1; dst = W1T; R = K1; C = C_REAL; KP = K1;
    n0 = (b & 63) * 32; k0 = (b >> 6) * 32;
  } else if (b < 2016) {               // w2 (1960x512) -> W2T (512x1984)
    int bb = b - 1024;
    src = w2; dst = W2T; R = C_REAL; C = N2; KP = K2;
    n0 = (bb & 15) * 32; k0 = (bb >> 4) * 32;
  } else {                             // zero G K-pad cols (11520*24 elems)
    int i = (b - 2016) * 256 + tid;
    int r = i / 24, j = i - r * 24;
    G[(size_t)r * K2 + C_REAL + j] = 0;
    return;
  }
  const int tx = tid & 31, ty = tid >> 5;
  #pragma unroll
  for (int r = 0; r < 4; ++r) {
    int k = k0 + ty + 8 * r, n = n0 + tx;
    T[ty + 8 * r][tx] = (k < R && n < C) ? src[(size_t)k * C + n] : 0.f;
  }
  __syncthreads();
  #pragma unroll
  for (int r = 0; r < 4; ++r) {
    int n = n0 + ty + 8 * r, k = k0 + tx;
    if (k < KP) dst[(size_t)n * KP + k] = f2b(T[tx][ty + 8 * r]);
  }
}

__device__ __forceinline__ void stv(float v, float* p) { *p = v; }
__device__ __forceinline__ void stv(float v, u16* p) { *p = f2b(v); }

// ------- GEMM1: 256x128 tile, 512 thr (8 waves of 64x64), BK=64, XOR swizzle,
// global_load_lds width-16 staging. Emits bf16 into plane-major fold layout.
__global__ __launch_bounds__(512) void gemm1_fold(
    const u16* __restrict__ A, const u16* __restrict__ BT,
    const float* __restrict__ bias, u16* __restrict__ C)
{
  __shared__ u16 As[256 * 64];   // 32 KB
  __shared__ u16 Bs[128 * 64];   // 16 KB
  const int K = K1, N = N1;
  const int tid = threadIdx.x;
  const int bm = blockIdx.y * 256, bn = blockIdx.x * 128;
  const int wave = tid >> 6, lane = tid & 63;
  const int quad = lane >> 4, l16 = lane & 15;
  const int wm = (wave >> 1) * 64, wn = (wave & 1) * 64;
  const int srow = lane >> 3;                      // 0..7
  const int scol = ((lane & 7) ^ srow) * 8;        // swizzled source chunk

  const u16* pA = A + (size_t)(bm + wave * 32 + srow) * K + scol;
  const u16* pB = BT + (size_t)(bn + wave * 16 + srow) * K + scol;
  u16* lA = As + (wave * 32) * 64;
  u16* lB = Bs + (wave * 16) * 64;

  v4f acc[4][4];
  #pragma unroll
  for (int i = 0; i < 4; ++i)
    #pragma unroll
    for (int j = 0; j < 4; ++j) acc[i][j] = (v4f){0.f, 0.f, 0.f, 0.f};

  for (int k0 = 0; k0 < K; k0 += 64) {
    #pragma unroll
    for (int q = 0; q < 4; ++q)
      gl2lds16(pA + (size_t)(q * 8) * K, lA + q * 8 * 64);
    #pragma unroll
    for (int q = 0; q < 2; ++q)
      gl2lds16(pB + (size_t)(q * 8) * K, lB + q * 8 * 64);
    pA += 64; pB += 64;
    __syncthreads();
    #pragma unroll
    for (int h = 0; h < 2; ++h) {
      v8s af[4], bf[4];
      #pragma unroll
      for (int i = 0; i < 4; ++i) {
        int row = wm + i * 16 + l16;
        int ck = (h * 4 + quad) ^ (row & 7);
        af[i] = *(const v8s*)&As[row * 64 + ck * 8];
      }
      #pragma unroll
      for (int j = 0; j < 4; ++j) {
        int row = wn + j * 16 + l16;
        int ck = (h * 4 + quad) ^ (row & 7);
        bf[j] = *(const v8s*)&Bs[row * 64 + ck * 8];
      }
      #pragma unroll
      for (int i = 0; i < 4; ++i)
        #pragma unroll
        for (int j = 0; j < 4; ++j)
          acc[i][j] = __builtin_amdgcn_mfma_f32_16x16x32_bf16(af[i], bf[j], acc[i][j], 0, 0, 0);
    }
    __syncthreads();
  }

  #pragma unroll
  for (int i = 0; i < 4; ++i) {
    #pragma unroll
    for (int j = 0; j < 4; ++j) {
      int col = bn + wn + j * 16 + l16;
      if (col >= C_REAL) continue;
      float bv = bias[col];
      int ch = col / 49, t = col - ch * 49;
      #pragma unroll
      for (int r = 0; r < 4; ++r) {
        int row = bm + wm + i * 16 + quad * 4 + r;
        int bt = row / 720, v = row - bt * 720;
        C[(size_t)(bt * 40 + ch) * PLANE_ELEMS + v * TPAD + t] = f2b(acc[i][j][r] + bv);
      }
    }
  }
}

// ------- GEMM2: 128x128 tile, BK=64, fp32 out
__global__ __launch_bounds__(256) void gemm2(
    const u16* __restrict__ A, const u16* __restrict__ BT,
    const float* __restrict__ bias, float* __restrict__ C)
{
  __shared__ u16 As[128 * 64];
  __shared__ u16 Bs[128 * 64];
  const int K = K2, N = N2;
  const int tid = threadIdx.x;
  const int bm = blockIdx.y * 128, bn = blockIdx.x * 128;
  const int wave = tid >> 6, lane = tid & 63;
  const int quad = lane >> 4, l16 = lane & 15;
  const int wm = (wave >> 1) * 64, wn = (wave & 1) * 64;
  const int srow = lane >> 3;
  const int scol = ((lane & 7) ^ srow) * 8;

  const u16* pA = A + (size_t)(bm + wave * 32 + srow) * K + scol;
  const u16* pB = BT + (size_t)(bn + wave * 32 + srow) * K + scol;
  u16* lA = As + (wave * 32) * 64;
  u16* lB = Bs + (wave * 32) * 64;

  v4f acc[4][4];
  #pragma unroll
  for (int i = 0; i < 4; ++i)
    #pragma unroll
    for (int j = 0; j < 4; ++j) acc[i][j] = (v4f){0.f, 0.f, 0.f, 0.f};

  for (int k0 = 0; k0 < K; k0 += 64) {
    #pragma unroll
    for (int q = 0; q < 4; ++q) {
      gl2lds16(pA + (size_t)(q * 8) * K, lA + q * 8 * 64);
      gl2lds16(pB + (size_t)(q * 8) * K, lB + q * 8 * 64);
    }
    pA += 64; pB += 64;
    __syncthreads();
    #pragma unroll
    for (int h = 0; h < 2; ++h) {
      v8s af[4], bf[4];
      #pragma unroll
      for (int i = 0; i < 4; ++i) {
        int row = wm + i * 16 + l16;
        int ck = (h * 4 + quad) ^ (row & 7);
        af[i] = *(const v8s*)&As[row * 64 + ck * 8];
      }
      #pragma unroll
      for (int j = 0; j < 4; ++j) {
        int row = wn + j * 16 + l16;
        int ck = (h * 4 + quad) ^ (row & 7);
        bf[j] = *(const v8s*)&Bs[row * 64 + ck * 8];
      }
      #pragma unroll
      for (int i = 0; i < 4; ++i)
        #pragma unroll
        for (int j = 0; j < 4; ++j)
          acc[i][j] = __builtin_amdgcn_mfma_f32_16x16x32_bf16(af[i], bf[j], acc[i][j], 0, 0, 0);
    }
    __syncthreads();
  }

  #pragma unroll
  for (int i = 0; i < 4; ++i) {
    #pragma unroll
    for (int j = 0; j < 4; ++j) {
      int col = bn + wn + j * 16 + l16;
      float bv = bias[col];
      #pragma unroll
      for (int r = 0; r < 4; ++r) {
        int row = bm + wm + i * 16 + quad * 4 + r;
        C[(size_t)row * N + col] = acc[i][j][r] + bv;
      }
    }
  }
}

// ------- fold + normalize, gather formulation, strip granularity (grid 3x640)
__global__ __launch_bounds__(256) void fold_norm(const u16* __restrict__ Aw,
                                                 float* __restrict__ Sn)
{
  __shared__ u16 raw[10 * HROW];          // 40,320 B
  const int plane = blockIdx.y;
  const int r0 = blockIdx.x * 22;
  const int tid = threadIdx.x;
  const int hlo = max(0, (r0 - 6) / 3);
  const int hhi = min(19, (r0 + 21) / 3);
  const int nchunks = (hhi - hlo + 1) * (HROW / 8);
  const int4* src = (const int4*)(Aw + (size_t)plane * PLANE_ELEMS + hlo * HROW);
  int4* dst = (int4*)raw;
  for (int j = tid; j < nchunks; j += 256) dst[j] = src[j];
  __syncthreads();

  float* out = Sn + (size_t)plane * 7524 + r0 * 114;
  for (int i = tid; i < 22 * 114; i += 256) {
    int r = i / 114, px = i - r * 114;
    int py = r0 + r;
    float val = 0.f;
    if (py >= 3 && py < 63 && px >= 3 && px < 111) {
      int ry = py % 3, rx = px % 3;
      int hhs[3], kis[3], nki = 0;
      #pragma unroll
      for (int k = 0; k < 3; ++k) {
        int ki = ry + 3 * k;
        if (ki < 7 && py - ki >= 0) {
          int hh = (py - ki) / 3;
          if (hh < 20) { kis[nki] = ki; hhs[nki] = hh; ++nki; }
        }
      }
      int wws[3], kjs[3], nkj = 0;
      #pragma unroll
      for (int k = 0; k < 3; ++k) {
        int kj = rx + 3 * k;
        if (kj < 7 && px - kj >= 0) {
          int ww = (px - kj) / 3;
          if (ww < 36) { kjs[nkj] = kj; wws[nkj] = ww; ++nkj; }
        }
      }
      float sum = 0.f;
      for (int a = 0; a < nki; ++a) {
        int rowoff = (hhs[a] - hlo) * HROW + kis[a] * 7;
        for (int b = 0; b < nkj; ++b)
          sum += b2f(raw[rowoff + wws[b] * TPAD + kjs[b]]);
      }
      val = sum / (float)(nki * nkj);
    }
    out[i] = val;
  }
}

// ------- full-height rolling-window dwconv + GELU: 20 output rows per column.
template<int KS>
__device__ __forceinline__ void conv_col(const float* __restrict__ Sl,
    const float* __restrict__ Wl, const float* __restrict__ Bl,
    u16* __restrict__ G, int bt, int colbase, int tid)
{
  constexpr int P = KS / 2;
  for (int idx = tid; idx < 36 * 49; idx += 512) {
    int wo = idx / 49, t = idx - wo * 49;
    int ki = t / 7, kj = t - ki * 7;
    float wgt[KS * KS];
    #pragma unroll
    for (int j = 0; j < KS * KS; ++j) wgt[j] = Wl[t * KS * KS + j];
    const float bias = Bl[t];
    int sx[KS]; bool vx[KS];
    #pragma unroll
    for (int dx = 0; dx < KS; ++dx) {
      int wq = wo + dx - P;
      vx[dx] = (wq >= 0 && wq < 36);
      sx[dx] = wq * 3 + kj;
    }
    float win[KS][KS];
    #pragma unroll
    for (int dy = 0; dy < KS; ++dy) {
      int hq = dy - P;
      #pragma unroll
      for (int dx = 0; dx < KS; ++dx)
        win[dy][dx] = (hq >= 0 && vx[dx]) ? Sl[(hq * 3 + ki) * 114 + sx[dx]] : 0.f;
    }
    u16* gp = G + (size_t)(bt * 720 + wo) * K2 + colbase + t;
    for (int h = 0; h < 20; ++h) {
      float y = bias;
      #pragma unroll
      for (int dy = 0; dy < KS; ++dy)
        #pragma unroll
        for (int dx = 0; dx < KS; ++dx)
          y += wgt[dy * KS + dx] * win[dy][dx];
      float g = 0.5f * y * (1.0f + erff(y * 0.70710678118654752f));
      *gp = f2b(g);
      gp += (size_t)36 * K2;
      if (h < 19) {
        #pragma unroll
        for (int dy = 0; dy < KS - 1; ++dy)
          #pragma unroll
          for (int dx = 0; dx < KS; ++dx) win[dy][dx] = win[dy + 1][dx];
        int hq = h + 1 + P;
        #pragma unroll
        for (int dx = 0; dx < KS; ++dx)
          win[KS - 1][dx] = (hq < 20 && vx[dx])
                              ? Sl[(hq * 3 + ki) * 114 + sx[dx]] : 0.f;
      }
    }
  }
}

__global__ __launch_bounds__(512) void dwconv_gelu3(const float* __restrict__ Sn,
    const float* __restrict__ w3, const float* __restrict__ b3,
    const float* __restrict__ w5, const float* __restrict__ b5,
    u16* __restrict__ G)
{
  __shared__ float Sl[66 * 114];     // 30,096 B
  __shared__ float Wl[49 * 25];
  __shared__ float Bl[49];
  const int plane = blockIdx.x, bt = plane / 40, ch = plane % 40;
  const int tid = threadIdx.x;
  const int colbase = ch * 49;
  const bool is3 = (ch < 20);
  if (is3) {
    for (int i = tid; i < 49 * 9; i += 512) Wl[i] = w3[colbase * 9 + i];
    if (tid < 49) Bl[tid] = b3[colbase + tid];
  } else {
    int c5 = colbase - 980;
    for (int i = tid; i < 49 * 25; i += 512) Wl[i] = w5[c5 * 25 + i];
    if (tid < 49) Bl[tid] = b5[c5 + tid];
  }
  const float4* sp = (const float4*)(Sn + (size_t)plane * 7524);
  float4* sl4 = (float4*)Sl;
  for (int i = tid; i < 7524 / 4; i += 512) sl4[i] = sp[i];
  __syncthreads();
  if (is3) conv_col<3>(Sl, Wl, Bl, G, bt, colbase, tid);
  else     conv_col<5>(Sl, Wl, Bl, G, bt, colbase, tid);
}

extern "C" void kernel_launch(void* const* d_in, const int* in_sizes, int n_in,
                              void* d_out, int out_size, void* d_ws, size_t ws_size,
                              hipStream_t stream) {
  const float* x  = (const float*)d_in[0];
  const float* w1 = (const float*)d_in[1];
  const float* b1 = (const float*)d_in[2];
  const float* w3 = (const float*)d_in[3];
  const float* b3 = (const float*)d_in[4];
  const float* w5 = (const float*)d_in[5];
  const float* b5 = (const float*)d_in[6];
  const float* w2 = (const float*)d_in[7];
  const float* b2 = (const float*)d_in[8];
  float* out = (float*)d_out;

  char* ws = (char*)d_ws;
  u16*   Xb  = (u16*)(ws);                   // 11520*512  bf16 = 11,796,480
  u16*   W1T = (u16*)(ws + 11796480);        // 2048*512   bf16 =  2,097,152
  u16*   W2T = (u16*)(ws + 13893632);        // 512*1984   bf16 =  2,031,616
  u16*   Aw  = (u16*)(ws + 15925248);        // 640*40320  bf16 = 51,609,600 (fold layout)
  u16*   G   = (u16*)(ws + 67534848);        // 11520*1984 bf16 = 45,711,360
  float* Sn  = (float*)(ws + 113246208);     // 640*7524   fp32 = 19,261,440 -> 132,507,648 total

  hipLaunchKernelGGL(prep, dim3(5976), dim3(256), 0, stream,
                     x, Xb, w1, W1T, w2, W2T, G);
  hipLaunchKernelGGL(gemm1_fold, dim3(N1 / 128, M_ROWS / 256), dim3(512), 0, stream,
                     Xb, W1T, b1, Aw);
  hipLaunchKernelGGL(fold_norm, dim3(3, 640), dim3(256), 0, stream, Aw, Sn);
  hipLaunchKernelGGL(dwconv_gelu3, dim3(640), dim3(512), 0, stream,
                     Sn, w3, b3, w5, b5, G);
  hipLaunchKernelGGL(gemm2, dim3(N2 / 128, M_ROWS / 128), dim3(256), 0, stream,
                     G, W2T, b2, out);
}